// Round 15
// baseline (5179.595 us; speedup 1.0000x reference)
//
#include <hip/hip_runtime.h>
#include <cstdint>
#include <cstddef>

#define B_SZ 32
#define NPTS 16384
#define NSAMP 2048
#define F_IN 64
#define C_IN 67
#define D_OUT 128
#define FPS_THREADS 1024
#define PPT 16                     // points (slices) per thread (wave)
#define NWAVE 16
#define NCELL 512                  // 8x8x8 Morton cells

// ---- DPP wave reduce helpers (row_shr 1/2/4/8 + row_bcast 15/31 -> lane63) ----
template <int CTRL>
__device__ __forceinline__ float dpp_maxf(float v) {
    const int iv = __float_as_int(v);
    const int mv = __builtin_amdgcn_update_dpp(iv, iv, CTRL, 0xf, 0xf, false);
    return fmaxf(v, __int_as_float(mv));
}
template <int CTRL>
__device__ __forceinline__ float dpp_minf(float v) {
    const int iv = __float_as_int(v);
    const int mv = __builtin_amdgcn_update_dpp(iv, iv, CTRL, 0xf, 0xf, false);
    return fminf(v, __int_as_float(mv));
}
__device__ __forceinline__ float wave_max_all(float v) {
    v = dpp_maxf<0x111>(v); v = dpp_maxf<0x112>(v); v = dpp_maxf<0x114>(v);
    v = dpp_maxf<0x118>(v); v = dpp_maxf<0x142>(v); v = dpp_maxf<0x143>(v);
    return __shfl(v, 63, 64);
}
__device__ __forceinline__ float wave_min_all(float v) {
    v = dpp_minf<0x111>(v); v = dpp_minf<0x112>(v); v = dpp_minf<0x114>(v);
    v = dpp_minf<0x118>(v); v = dpp_minf<0x142>(v); v = dpp_minf<0x143>(v);
    return __shfl(v, 63, 64);
}
template <int CTRL>
__device__ __forceinline__ unsigned long long dpp_key_max(unsigned long long key) {
    const int lo = (int)(unsigned)key;
    const int hi = (int)(unsigned)(key >> 32);
    const int lo2 = __builtin_amdgcn_update_dpp(lo, lo, CTRL, 0xf, 0xf, false);
    const int hi2 = __builtin_amdgcn_update_dpp(hi, hi, CTRL, 0xf, 0xf, false);
    const unsigned long long ok =
        ((unsigned long long)(unsigned)hi2 << 32) | (unsigned long long)(unsigned)lo2;
    return ok > key ? ok : key;
}

// ---------------------------------------------------------------------------
// FPS, R13 two-level exact skip + centroid routed through LDS:
//   - wave-level bbox skip (cached key) + slice-level ballot skip; both
//     conservative (1e-5 slack >> fp error -> fminf provably no-op on
//     skipped sets) -> bit-identical trajectory (absmax 0 since R11).
//   - bo-scan (min ORIGINAL index among dist==best, = jnp.argmax tie rule)
//     also selects the candidate's coords into registers.
//   - after the u64 DPP butterfly, the unique lane whose own key equals the
//     wave key writes {x,y,z} to parity-slotted s_cand[q][wave]; skipped
//     waves copy s_cand[q^1][wave] -> s_cand[q][wave] (lane0, off the
//     critical path). All waves active at s=0 -> induction holds.
//   - post-barrier: serial 16-key reduce ALSO tracks the winning wave index;
//     centroid = ds_read_b128 of s_cand[q][wix] (~120cy) — replaces the
//     readfirstlane + uniform global L2 load (~200-300cy) on the serial tail.
// ---------------------------------------------------------------------------
__global__ __launch_bounds__(FPS_THREADS, 4)
void fps_kernel(const float* __restrict__ xyz,       // [B, N, 3]
                const int* __restrict__ init_far,    // [B]
                int* __restrict__ idx_out,           // [B, S]
                float* __restrict__ newxyz_out)      // [B, S, 3]
{
    const int b = blockIdx.x;
    const int tid = threadIdx.x;
    const int lane = tid & 63;
    const int wave = tid >> 6;
    const float* base = xyz + (size_t)b * NPTS * 3;

    __shared__ unsigned short s_sidx[NPTS];          // 32 KB sorted orig idx
    __shared__ unsigned int s_hist[NCELL];
    __shared__ unsigned int s_start[NCELL];
    __shared__ unsigned long long s_key[2][NWAVE];
    __shared__ float4 s_cand[2][NWAVE];

    // ---- phase 0/1: cell ids + histogram ----
    if (tid < NCELL) s_hist[tid] = 0u;
    __syncthreads();

    unsigned cells[PPT];
#pragma unroll
    for (int p = 0; p < PPT; ++p) {
        const int i = tid + p * FPS_THREADS;
        const float x = base[i * 3 + 0];
        const float y = base[i * 3 + 1];
        const float z = base[i * 3 + 2];
        const int qx = (int)fminf(fmaxf((x + 3.0f) * 1.3333333f, 0.0f), 7.0f);
        const int qy = (int)fminf(fmaxf((y + 3.0f) * 1.3333333f, 0.0f), 7.0f);
        const int qz = (int)fminf(fmaxf((z + 3.0f) * 1.3333333f, 0.0f), 7.0f);
        unsigned m = 0;
#pragma unroll
        for (int t = 0; t < 3; ++t)
            m |= (((unsigned)(qx >> t) & 1u) << (3 * t + 2)) |
                 (((unsigned)(qy >> t) & 1u) << (3 * t + 1)) |
                 (((unsigned)(qz >> t) & 1u) << (3 * t + 0));
        cells[p] = m;
        atomicAdd(&s_hist[m], 1u);
    }
    __syncthreads();

    // ---- phase 2: exclusive prefix sum (Hillis-Steele) ----
    for (int off = 1; off < NCELL; off <<= 1) {
        unsigned v = 0;
        if (tid < NCELL) {
            v = s_hist[tid];
            if (tid >= off) v += s_hist[tid - off];
        }
        __syncthreads();
        if (tid < NCELL) s_hist[tid] = v;
        __syncthreads();
    }
    if (tid < NCELL) s_start[tid] = (tid == 0) ? 0u : s_hist[tid - 1];
    __syncthreads();

    // ---- phase 3: scatter orig indices into cell-sorted order ----
#pragma unroll
    for (int p = 0; p < PPT; ++p) {
        const int i = tid + p * FPS_THREADS;
        const unsigned pos = atomicAdd(&s_start[cells[p]], 1u);
        s_sidx[pos] = (unsigned short)i;
    }
    __syncthreads();

    // ---- phase 4: regather wave-contiguous points ----
    float px[PPT], py[PPT], pz[PPT], dist[PPT];
    unsigned oidx[PPT / 2];                          // packed u16 orig indices
#pragma unroll
    for (int p = 0; p < PPT; ++p) {
        const int spos = wave * 1024 + p * 64 + lane;
        const unsigned oi = (unsigned)s_sidx[spos];
        px[p] = base[oi * 3 + 0];
        py[p] = base[oi * 3 + 1];
        pz[p] = base[oi * 3 + 2];
        dist[p] = 1e10f;
        if (p & 1) oidx[p >> 1] |= oi << 16; else oidx[p >> 1] = oi;
    }

    // ---- phase 5: per-slice bboxes in lane p, wave bbox in all lanes ----
    float sbmnx = 0.f, sbmny = 0.f, sbmnz = 0.f;
    float sbmxx = 0.f, sbmxy = 0.f, sbmxz = 0.f;
    float wbmnx = 1e30f, wbmny = 1e30f, wbmnz = 1e30f;
    float wbmxx = -1e30f, wbmxy = -1e30f, wbmxz = -1e30f;
#pragma unroll
    for (int p = 0; p < PPT; ++p) {
        const float mnx = wave_min_all(px[p]);
        const float mny = wave_min_all(py[p]);
        const float mnz = wave_min_all(pz[p]);
        const float mxx = wave_max_all(px[p]);
        const float mxy = wave_max_all(py[p]);
        const float mxz = wave_max_all(pz[p]);
        const bool sel = (lane == p);
        sbmnx = sel ? mnx : sbmnx;  sbmny = sel ? mny : sbmny;
        sbmnz = sel ? mnz : sbmnz;  sbmxx = sel ? mxx : sbmxx;
        sbmxy = sel ? mxy : sbmxy;  sbmxz = sel ? mxz : sbmxz;
        wbmnx = fminf(wbmnx, mnx); wbmny = fminf(wbmny, mny);
        wbmnz = fminf(wbmnz, mnz); wbmxx = fmaxf(wbmxx, mxx);
        wbmxy = fmaxf(wbmxy, mxy); wbmxz = fmaxf(wbmxz, mxz);
    }

    float wmax_u = 1e10f;                // wave's current max dist (uniform)
    unsigned long long ckey = 0ull;      // cached wave key (lane63's is real)

    int cur = init_far[b];
    float cx = base[cur * 3 + 0];
    float cy = base[cur * 3 + 1];
    float cz = base[cur * 3 + 2];
    __syncthreads();

    for (int s = 0; s < NSAMP; ++s) {
        const int q = s & 1;
        // record BEFORE update (reference scan semantics)
        if (tid == 0) {
            idx_out[b * NSAMP + s] = cur;
            float* o = newxyz_out + (size_t)(b * NSAMP + s) * 3;
            o[0] = cx; o[1] = cy; o[2] = cz;
        }

        // level 1: wave bbox lower bound (uniform -> s_cbranch)
        const float wdx = fmaxf(fmaxf(wbmnx - cx, cx - wbmxx), 0.0f);
        const float wdy = fmaxf(fmaxf(wbmny - cy, cy - wbmxy), 0.0f);
        const float wdz = fmaxf(fmaxf(wbmnz - cz, cz - wbmxz), 0.0f);
        const float Lw = wdx * wdx + wdy * wdy + wdz * wdz;

        if (Lw * 0.99999f <= wmax_u) {
            // level 2: per-slice bounds via lane p + ballot
            const float dxl = fmaxf(fmaxf(sbmnx - cx, cx - sbmxx), 0.0f);
            const float dyl = fmaxf(fmaxf(sbmny - cy, cy - sbmxy), 0.0f);
            const float dzl = fmaxf(fmaxf(sbmnz - cz, cz - sbmxz), 0.0f);
            const float L = dxl * dxl + dyl * dyl + dzl * dzl;
            const unsigned long long bal = __ballot(L * 0.99999f <= wmax_u);
            const unsigned amask =
                __builtin_amdgcn_readfirstlane((unsigned)bal) & 0xFFFFu;

            // dist update per flagged slice (wave-uniform branches)
#pragma unroll
            for (int p = 0; p < PPT; ++p) {
                if (amask & (1u << p)) {
                    const float dx = __fsub_rn(px[p], cx);
                    const float dy = __fsub_rn(py[p], cy);
                    const float dz = __fsub_rn(pz[p], cz);
                    const float d  = __fadd_rn(__fadd_rn(__fmul_rn(dx, dx),
                                                         __fmul_rn(dy, dy)),
                                               __fmul_rn(dz, dz));
                    dist[p] = fminf(dist[p], d);
                }
            }

            // exact per-thread max over all 16 slices
            float best = 0.0f;
#pragma unroll
            for (int p = 0; p < PPT; p += 2)
                best = fmaxf(fmaxf(best, dist[p]), dist[p + 1]);   // v_max3

            // min ORIGINAL index among exact matches + candidate coords
            unsigned bo = 0xFFFFFFFFu;
            float wcx = 0.f, wcy = 0.f, wcz = 0.f;
#pragma unroll
            for (int p = 0; p < PPT; ++p) {
                const unsigned oi = (oidx[p >> 1] >> ((p & 1) * 16)) & 0xFFFFu;
                const bool cond = (dist[p] == best) && (oi < bo);
                bo  = cond ? oi    : bo;
                wcx = cond ? px[p] : wcx;
                wcy = cond ? py[p] : wcy;
                wcz = cond ? pz[p] : wcz;
            }
            unsigned long long key =
                ((unsigned long long)__float_as_uint(best) << 32) |
                (unsigned long long)(~bo);
            const unsigned long long okey = key;     // own key, pre-butterfly
            key = dpp_key_max<0x111>(key);
            key = dpp_key_max<0x112>(key);
            key = dpp_key_max<0x114>(key);
            key = dpp_key_max<0x118>(key);
            key = dpp_key_max<0x142>(key);
            key = dpp_key_max<0x143>(key);
            ckey = key;                              // lane63 holds wave key
            wmax_u = __shfl(__uint_as_float((unsigned)(key >> 32)), 63, 64);
            // unique winner lane (keys are unique: bo is unique per point)
            if (okey == __shfl((long long)key, 63, 64) * 0 + key && okey == key) {}
            if (okey == key) {
                s_cand[q][wave] = float4{wcx, wcy, wcz, 0.f};
            }
        } else {
            // skipped wave: carry cached candidate into current parity slot
            if (lane == 0) s_cand[q][wave] = s_cand[q ^ 1][wave];
        }

        if (lane == 63) s_key[q][wave] = ckey;
        __syncthreads();                             // the only barrier

        // serial 16-key reduce, tracking the winning wave index
        unsigned long long fin = s_key[q][0];
        int wix = 0;
#pragma unroll
        for (int w = 1; w < NWAVE; ++w) {
            const unsigned long long k2 = s_key[q][w];
            const bool g = k2 > fin;
            fin = g ? k2 : fin;
            wix = g ? w : wix;
        }
        const int vi = (int)(~(unsigned)(fin & 0xFFFFFFFFull));
        cur = vi;
        const float4 cand = s_cand[q][wix];          // broadcast LDS read
        cx = cand.x; cy = cand.y; cz = cand.z;
    }
}

// ---------------------------------------------------------------------------
// Kernel 2: gather selected rows, 1x1 conv (x @ W + b), ReLU.
// ---------------------------------------------------------------------------
#define SAMP_PER_BLK 16

__global__ __launch_bounds__(256)
void gather_linear_relu_kernel(const float* __restrict__ xyz,    // [B,N,3]
                               const float* __restrict__ feats,  // [B,N,F]
                               const int* __restrict__ idx,      // [B*S]
                               const float* __restrict__ W,      // [67,128]
                               const float* __restrict__ bias,   // [128]
                               float* __restrict__ out)          // [B*S,128]
{
    __shared__ float sW[C_IN][D_OUT];
    __shared__ float sX[SAMP_PER_BLK][C_IN + 1];
    __shared__ float sB[D_OUT];

    const int tid = threadIdx.x;

    for (int i = tid; i < C_IN * D_OUT; i += 256)
        (&sW[0][0])[i] = W[i];
    if (tid < D_OUT) sB[tid] = bias[tid];

    const int gs0 = blockIdx.x * SAMP_PER_BLK;

    {
        const int si = tid >> 4;
        const int j  = tid & 15;
        const int gs = gs0 + si;
        const int bb = gs >> 11;
        const int pt = idx[gs];
        const float* frow = feats + ((size_t)bb * NPTS + pt) * F_IN;
        const float* xrow = xyz   + ((size_t)bb * NPTS + pt) * 3;
        for (int c = j; c < F_IN; c += 16) sX[si][c] = frow[c];
        if (j < 3) sX[si][F_IN + j] = xrow[j];
    }
    __syncthreads();

    const int d = tid & 127;
    const int g = tid >> 7;
    float acc[8];
#pragma unroll
    for (int k = 0; k < 8; ++k) acc[k] = 0.0f;

    for (int c = 0; c < C_IN; ++c) {
        const float w = sW[c][d];
#pragma unroll
        for (int k = 0; k < 8; ++k)
            acc[k] = fmaf(sX[g * 8 + k][c], w, acc[k]);
    }

    const float bv = sB[d];
#pragma unroll
    for (int k = 0; k < 8; ++k) {
        const int gs = gs0 + g * 8 + k;
        const float v = acc[k] + bv;
        out[(size_t)gs * D_OUT + d] = fmaxf(v, 0.0f);
    }
}

// ---------------------------------------------------------------------------
extern "C" void kernel_launch(void* const* d_in, const int* in_sizes, int n_in,
                              void* d_out, int out_size, void* d_ws, size_t ws_size,
                              hipStream_t stream) {
    const float* xyz      = (const float*)d_in[0];
    const float* feats    = (const float*)d_in[1];
    const int*   init_far = (const int*)d_in[2];
    const float* W        = (const float*)d_in[3];
    const float* bias     = (const float*)d_in[4];

    float* out_newxyz = (float*)d_out;
    float* out_conv   = (float*)d_out + (size_t)B_SZ * NSAMP * 3;
    int*   idx_ws     = (int*)d_ws;

    fps_kernel<<<B_SZ, FPS_THREADS, 0, stream>>>(xyz, init_far, idx_ws, out_newxyz);

    const int nblocks = (B_SZ * NSAMP) / SAMP_PER_BLK;
    gather_linear_relu_kernel<<<nblocks, 256, 0, stream>>>(
        xyz, feats, idx_ws, W, bias, out_conv);
}

// Round 16
// 2434.844 us; speedup vs baseline: 2.1273x; 2.1273x over previous
//
#include <hip/hip_runtime.h>
#include <cstdint>
#include <cstddef>

#define B_SZ 32
#define NPTS 16384
#define NSAMP 2048
#define F_IN 64
#define C_IN 67
#define D_OUT 128
#define FPS_THREADS 1024
#define PPT 16                     // points (slices) per thread (wave)
#define NWAVE 16
#define NCELL 4096                 // 16x16x16 Morton cells
#define CPT (NCELL / FPS_THREADS)  // 4 cells per thread in the scan

// ---- DPP wave reduce helpers (row_shr 1/2/4/8 + row_bcast 15/31 -> lane63) ----
template <int CTRL>
__device__ __forceinline__ float dpp_maxf(float v) {
    const int iv = __float_as_int(v);
    const int mv = __builtin_amdgcn_update_dpp(iv, iv, CTRL, 0xf, 0xf, false);
    return fmaxf(v, __int_as_float(mv));
}
template <int CTRL>
__device__ __forceinline__ float dpp_minf(float v) {
    const int iv = __float_as_int(v);
    const int mv = __builtin_amdgcn_update_dpp(iv, iv, CTRL, 0xf, 0xf, false);
    return fminf(v, __int_as_float(mv));
}
__device__ __forceinline__ float wave_max_all(float v) {
    v = dpp_maxf<0x111>(v); v = dpp_maxf<0x112>(v); v = dpp_maxf<0x114>(v);
    v = dpp_maxf<0x118>(v); v = dpp_maxf<0x142>(v); v = dpp_maxf<0x143>(v);
    return __shfl(v, 63, 64);
}
__device__ __forceinline__ float wave_min_all(float v) {
    v = dpp_minf<0x111>(v); v = dpp_minf<0x112>(v); v = dpp_minf<0x114>(v);
    v = dpp_minf<0x118>(v); v = dpp_minf<0x142>(v); v = dpp_minf<0x143>(v);
    return __shfl(v, 63, 64);
}
template <int CTRL>
__device__ __forceinline__ unsigned long long dpp_key_max(unsigned long long key) {
    const int lo = (int)(unsigned)key;
    const int hi = (int)(unsigned)(key >> 32);
    const int lo2 = __builtin_amdgcn_update_dpp(lo, lo, CTRL, 0xf, 0xf, false);
    const int hi2 = __builtin_amdgcn_update_dpp(hi, hi, CTRL, 0xf, 0xf, false);
    const unsigned long long ok =
        ((unsigned long long)(unsigned)hi2 << 32) | (unsigned long long)(unsigned)lo2;
    return ok > key ? ok : key;
}

// ---------------------------------------------------------------------------
// FPS, R13 two-level exact skip, with a 16^3 Morton grid (4096 cells):
// tighter slice bboxes (diag ~0.65 vs ~1.3) -> fewer false-active slices and
// waves in the mid/late phase where R13 spends its time. Main loop is
// byte-identical to R13 (best-known reduce path: register oidx, u64 DPP
// butterfly, linear 16-key reduce, scalar centroid load — R14/R15 proved
// every "improvement" there adds latency or spills).
// Exactness: conservative bbox bounds (1e-5 slack >> fp error) make fminf a
// provable no-op on skipped sets; tie-break = min ORIGINAL index -> bit-
// identical jnp.argmax trajectory (absmax 0 since R11).
// ---------------------------------------------------------------------------
__global__ __launch_bounds__(FPS_THREADS, 4)
void fps_kernel(const float* __restrict__ xyz,       // [B, N, 3]
                const int* __restrict__ init_far,    // [B]
                int* __restrict__ idx_out,           // [B, S]
                float* __restrict__ newxyz_out)      // [B, S, 3]
{
    const int b = blockIdx.x;
    const int tid = threadIdx.x;
    const int lane = tid & 63;
    const int wave = tid >> 6;
    const float* base = xyz + (size_t)b * NPTS * 3;

    __shared__ unsigned short s_sidx[NPTS];          // 32 KB sorted orig idx
    __shared__ unsigned int s_hist[NCELL];           // 16 KB hist -> starts
    __shared__ unsigned int s_part[FPS_THREADS];     // 4 KB scan partials
    __shared__ unsigned long long s_key[2][NWAVE];

    // ---- phase 0/1: cell ids + histogram (16^3 grid over [-3,3]) ----
    for (int i = tid; i < NCELL; i += FPS_THREADS) s_hist[i] = 0u;
    __syncthreads();

    unsigned cells[PPT];
#pragma unroll
    for (int p = 0; p < PPT; ++p) {
        const int i = tid + p * FPS_THREADS;
        const float x = base[i * 3 + 0];
        const float y = base[i * 3 + 1];
        const float z = base[i * 3 + 2];
        const int qx = (int)fminf(fmaxf((x + 3.0f) * 2.6666667f, 0.0f), 15.0f);
        const int qy = (int)fminf(fmaxf((y + 3.0f) * 2.6666667f, 0.0f), 15.0f);
        const int qz = (int)fminf(fmaxf((z + 3.0f) * 2.6666667f, 0.0f), 15.0f);
        unsigned m = 0;
#pragma unroll
        for (int t = 0; t < 4; ++t)
            m |= (((unsigned)(qx >> t) & 1u) << (3 * t + 2)) |
                 (((unsigned)(qy >> t) & 1u) << (3 * t + 1)) |
                 (((unsigned)(qz >> t) & 1u) << (3 * t + 0));
        cells[p] = m;
        atomicAdd(&s_hist[m], 1u);
    }
    __syncthreads();

    // ---- phase 2: exclusive scan over 4096 cells (two-stage) ----
    // stage A: each thread sums its 4 consecutive cells
    unsigned hh[CPT];
    unsigned tsum = 0;
#pragma unroll
    for (int j = 0; j < CPT; ++j) {
        hh[j] = s_hist[tid * CPT + j];
        tsum += hh[j];
    }
    s_part[tid] = tsum;
    __syncthreads();
    // stage B: Hillis-Steele inclusive scan over the 1024 partials
    for (int off = 1; off < FPS_THREADS; off <<= 1) {
        unsigned v = s_part[tid];
        if (tid >= off) v += s_part[tid - off];
        __syncthreads();
        s_part[tid] = v;
        __syncthreads();
    }
    // stage C: in-place exclusive starts for this thread's 4 cells
    {
        unsigned e = (tid == 0) ? 0u : s_part[tid - 1];
#pragma unroll
        for (int j = 0; j < CPT; ++j) {
            s_hist[tid * CPT + j] = e;
            e += hh[j];
        }
    }
    __syncthreads();

    // ---- phase 3: scatter orig indices into cell-sorted order ----
#pragma unroll
    for (int p = 0; p < PPT; ++p) {
        const int i = tid + p * FPS_THREADS;
        const unsigned pos = atomicAdd(&s_hist[cells[p]], 1u);
        s_sidx[pos] = (unsigned short)i;
    }
    __syncthreads();

    // ---- phase 4: regather wave-contiguous points ----
    float px[PPT], py[PPT], pz[PPT], dist[PPT];
    unsigned oidx[PPT / 2];                          // packed u16 orig indices
#pragma unroll
    for (int p = 0; p < PPT; ++p) {
        const int spos = wave * 1024 + p * 64 + lane;
        const unsigned oi = (unsigned)s_sidx[spos];
        px[p] = base[oi * 3 + 0];
        py[p] = base[oi * 3 + 1];
        pz[p] = base[oi * 3 + 2];
        dist[p] = 1e10f;
        if (p & 1) oidx[p >> 1] |= oi << 16; else oidx[p >> 1] = oi;
    }

    // ---- phase 5: per-slice bboxes in lane p, wave bbox in all lanes ----
    float sbmnx = 0.f, sbmny = 0.f, sbmnz = 0.f;
    float sbmxx = 0.f, sbmxy = 0.f, sbmxz = 0.f;
    float wbmnx = 1e30f, wbmny = 1e30f, wbmnz = 1e30f;
    float wbmxx = -1e30f, wbmxy = -1e30f, wbmxz = -1e30f;
#pragma unroll
    for (int p = 0; p < PPT; ++p) {
        const float mnx = wave_min_all(px[p]);
        const float mny = wave_min_all(py[p]);
        const float mnz = wave_min_all(pz[p]);
        const float mxx = wave_max_all(px[p]);
        const float mxy = wave_max_all(py[p]);
        const float mxz = wave_max_all(pz[p]);
        const bool sel = (lane == p);
        sbmnx = sel ? mnx : sbmnx;  sbmny = sel ? mny : sbmny;
        sbmnz = sel ? mnz : sbmnz;  sbmxx = sel ? mxx : sbmxx;
        sbmxy = sel ? mxy : sbmxy;  sbmxz = sel ? mxz : sbmxz;
        wbmnx = fminf(wbmnx, mnx); wbmny = fminf(wbmny, mny);
        wbmnz = fminf(wbmnz, mnz); wbmxx = fmaxf(wbmxx, mxx);
        wbmxy = fmaxf(wbmxy, mxy); wbmxz = fmaxf(wbmxz, mxz);
    }

    float wmax_u = 1e10f;                // wave's current max dist (uniform)
    unsigned long long ckey = 0ull;      // cached wave key (lane63's is real)

    int cur = init_far[b];
    float cx = base[cur * 3 + 0];
    float cy = base[cur * 3 + 1];
    float cz = base[cur * 3 + 2];
    __syncthreads();

    for (int s = 0; s < NSAMP; ++s) {
        const int q = s & 1;
        // record BEFORE update (reference scan semantics)
        if (tid == 0) {
            idx_out[b * NSAMP + s] = cur;
            float* o = newxyz_out + (size_t)(b * NSAMP + s) * 3;
            o[0] = cx; o[1] = cy; o[2] = cz;
        }

        // level 1: wave bbox lower bound (uniform -> s_cbranch)
        const float wdx = fmaxf(fmaxf(wbmnx - cx, cx - wbmxx), 0.0f);
        const float wdy = fmaxf(fmaxf(wbmny - cy, cy - wbmxy), 0.0f);
        const float wdz = fmaxf(fmaxf(wbmnz - cz, cz - wbmxz), 0.0f);
        const float Lw = wdx * wdx + wdy * wdy + wdz * wdz;

        if (Lw * 0.99999f <= wmax_u) {
            // level 2: per-slice bounds via lane p + ballot
            const float dxl = fmaxf(fmaxf(sbmnx - cx, cx - sbmxx), 0.0f);
            const float dyl = fmaxf(fmaxf(sbmny - cy, cy - sbmxy), 0.0f);
            const float dzl = fmaxf(fmaxf(sbmnz - cz, cz - sbmxz), 0.0f);
            const float L = dxl * dxl + dyl * dyl + dzl * dzl;
            const unsigned long long bal = __ballot(L * 0.99999f <= wmax_u);
            const unsigned amask =
                __builtin_amdgcn_readfirstlane((unsigned)bal) & 0xFFFFu;

            // dist update per flagged slice (wave-uniform branches)
#pragma unroll
            for (int p = 0; p < PPT; ++p) {
                if (amask & (1u << p)) {
                    const float dx = __fsub_rn(px[p], cx);
                    const float dy = __fsub_rn(py[p], cy);
                    const float dz = __fsub_rn(pz[p], cz);
                    const float d  = __fadd_rn(__fadd_rn(__fmul_rn(dx, dx),
                                                         __fmul_rn(dy, dy)),
                                               __fmul_rn(dz, dz));
                    dist[p] = fminf(dist[p], d);
                }
            }

            // exact per-thread max over all 16 slices
            float best = 0.0f;
#pragma unroll
            for (int p = 0; p < PPT; p += 2)
                best = fmaxf(fmaxf(best, dist[p]), dist[p + 1]);   // v_max3

            // min ORIGINAL index among exact matches (jnp.argmax tie rule)
            unsigned bo = 0xFFFFFFFFu;
#pragma unroll
            for (int p = 0; p < PPT; ++p) {
                const unsigned oi = (oidx[p >> 1] >> ((p & 1) * 16)) & 0xFFFFu;
                bo = (dist[p] == best) ? min(bo, oi) : bo;
            }
            unsigned long long key =
                ((unsigned long long)__float_as_uint(best) << 32) |
                (unsigned long long)(~bo);
            key = dpp_key_max<0x111>(key);
            key = dpp_key_max<0x112>(key);
            key = dpp_key_max<0x114>(key);
            key = dpp_key_max<0x118>(key);
            key = dpp_key_max<0x142>(key);
            key = dpp_key_max<0x143>(key);
            ckey = key;                              // lane63 holds wave key
            wmax_u = __shfl(__uint_as_float((unsigned)(key >> 32)), 63, 64);
        }

        if (lane == 63) s_key[q][wave] = ckey;
        __syncthreads();                             // the only barrier

        unsigned long long fin = s_key[q][0];
#pragma unroll
        for (int w = 1; w < NWAVE; ++w) {
            const unsigned long long k2 = s_key[q][w];
            fin = (k2 > fin) ? k2 : fin;
        }
        const int vi = (int)(~(unsigned)(fin & 0xFFFFFFFFull));
        cur = vi;
        const int vs = __builtin_amdgcn_readfirstlane(vi);
        cx = base[vs * 3 + 0];
        cy = base[vs * 3 + 1];
        cz = base[vs * 3 + 2];
    }
}

// ---------------------------------------------------------------------------
// Kernel 2: gather selected rows, 1x1 conv (x @ W + b), ReLU.
// ---------------------------------------------------------------------------
#define SAMP_PER_BLK 16

__global__ __launch_bounds__(256)
void gather_linear_relu_kernel(const float* __restrict__ xyz,    // [B,N,3]
                               const float* __restrict__ feats,  // [B,N,F]
                               const int* __restrict__ idx,      // [B*S]
                               const float* __restrict__ W,      // [67,128]
                               const float* __restrict__ bias,   // [128]
                               float* __restrict__ out)          // [B*S,128]
{
    __shared__ float sW[C_IN][D_OUT];
    __shared__ float sX[SAMP_PER_BLK][C_IN + 1];
    __shared__ float sB[D_OUT];

    const int tid = threadIdx.x;

    for (int i = tid; i < C_IN * D_OUT; i += 256)
        (&sW[0][0])[i] = W[i];
    if (tid < D_OUT) sB[tid] = bias[tid];

    const int gs0 = blockIdx.x * SAMP_PER_BLK;

    {
        const int si = tid >> 4;
        const int j  = tid & 15;
        const int gs = gs0 + si;
        const int bb = gs >> 11;
        const int pt = idx[gs];
        const float* frow = feats + ((size_t)bb * NPTS + pt) * F_IN;
        const float* xrow = xyz   + ((size_t)bb * NPTS + pt) * 3;
        for (int c = j; c < F_IN; c += 16) sX[si][c] = frow[c];
        if (j < 3) sX[si][F_IN + j] = xrow[j];
    }
    __syncthreads();

    const int d = tid & 127;
    const int g = tid >> 7;
    float acc[8];
#pragma unroll
    for (int k = 0; k < 8; ++k) acc[k] = 0.0f;

    for (int c = 0; c < C_IN; ++c) {
        const float w = sW[c][d];
#pragma unroll
        for (int k = 0; k < 8; ++k)
            acc[k] = fmaf(sX[g * 8 + k][c], w, acc[k]);
    }

    const float bv = sB[d];
#pragma unroll
    for (int k = 0; k < 8; ++k) {
        const int gs = gs0 + g * 8 + k;
        const float v = acc[k] + bv;
        out[(size_t)gs * D_OUT + d] = fmaxf(v, 0.0f);
    }
}

// ---------------------------------------------------------------------------
extern "C" void kernel_launch(void* const* d_in, const int* in_sizes, int n_in,
                              void* d_out, int out_size, void* d_ws, size_t ws_size,
                              hipStream_t stream) {
    const float* xyz      = (const float*)d_in[0];
    const float* feats    = (const float*)d_in[1];
    const int*   init_far = (const int*)d_in[2];
    const float* W        = (const float*)d_in[3];
    const float* bias     = (const float*)d_in[4];

    float* out_newxyz = (float*)d_out;
    float* out_conv   = (float*)d_out + (size_t)B_SZ * NSAMP * 3;
    int*   idx_ws     = (int*)d_ws;

    fps_kernel<<<B_SZ, FPS_THREADS, 0, stream>>>(xyz, init_far, idx_ws, out_newxyz);

    const int nblocks = (B_SZ * NSAMP) / SAMP_PER_BLK;
    gather_linear_relu_kernel<<<nblocks, 256, 0, stream>>>(
        xyz, feats, idx_ws, W, bias, out_conv);
}

// Round 17
// 2217.528 us; speedup vs baseline: 2.3358x; 1.0980x over previous
//
#include <hip/hip_runtime.h>
#include <cstdint>
#include <cstddef>

#define B_SZ 32
#define NPTS 16384
#define NSAMP 2048
#define F_IN 64
#define C_IN 67
#define D_OUT 128
#define FPS_THREADS 1024
#define PPT 16                     // points (slices) per thread (wave)
#define NWAVE 16
#define NCELL 4096                 // 16x16x16 Morton cells
#define CPT (NCELL / FPS_THREADS)  // 4 cells per thread in the scan

// ---- DPP wave reduce helpers ----
template <int CTRL>
__device__ __forceinline__ float dpp_maxf(float v) {
    const int iv = __float_as_int(v);
    const int mv = __builtin_amdgcn_update_dpp(iv, iv, CTRL, 0xf, 0xf, false);
    return fmaxf(v, __int_as_float(mv));
}
template <int CTRL>
__device__ __forceinline__ float dpp_minf(float v) {
    const int iv = __float_as_int(v);
    const int mv = __builtin_amdgcn_update_dpp(iv, iv, CTRL, 0xf, 0xf, false);
    return fminf(v, __int_as_float(mv));
}
__device__ __forceinline__ float wave_max_all(float v) {
    v = dpp_maxf<0x111>(v); v = dpp_maxf<0x112>(v); v = dpp_maxf<0x114>(v);
    v = dpp_maxf<0x118>(v); v = dpp_maxf<0x142>(v); v = dpp_maxf<0x143>(v);
    return __shfl(v, 63, 64);
}
__device__ __forceinline__ float wave_min_all(float v) {
    v = dpp_minf<0x111>(v); v = dpp_minf<0x112>(v); v = dpp_minf<0x114>(v);
    v = dpp_minf<0x118>(v); v = dpp_minf<0x142>(v); v = dpp_minf<0x143>(v);
    return __shfl(v, 63, 64);
}
template <int CTRL>
__device__ __forceinline__ unsigned long long dpp_key_max(unsigned long long key) {
    const int lo = (int)(unsigned)key;
    const int hi = (int)(unsigned)(key >> 32);
    const int lo2 = __builtin_amdgcn_update_dpp(lo, lo, CTRL, 0xf, 0xf, false);
    const int hi2 = __builtin_amdgcn_update_dpp(hi, hi, CTRL, 0xf, 0xf, false);
    const unsigned long long ok =
        ((unsigned long long)(unsigned)hi2 << 32) | (unsigned long long)(unsigned)lo2;
    return ok > key ? ok : key;
}

// ---------------------------------------------------------------------------
// FPS, R16 two-level exact skip + single-point block reduce:
//   - per-iteration block argmax is reduced ONCE by wave0 (16 lanes read the
//     16 wave keys, 4-level DPP row max -> lane15 writes s_fin[q]) instead of
//     redundantly by all 16 waves (16 LDS reads + 15-deep u64 chain each).
//     Costs a second barrier; saves ~60 VALU instr/wave/iter and shortens
//     the serial reduce chain.
//   - s_fin[q] written between barrier1/barrier2 of iter s, read after
//     barrier2; next write to the same slot is in iter s+2 -> race-free.
//   - everything else (skip tests, dist update, tie-break) identical to R16;
//     bit-identical trajectory (absmax 0 since R11).
// ---------------------------------------------------------------------------
__global__ __launch_bounds__(FPS_THREADS, 4)
void fps_kernel(const float* __restrict__ xyz,       // [B, N, 3]
                const int* __restrict__ init_far,    // [B]
                int* __restrict__ idx_out,           // [B, S]
                float* __restrict__ newxyz_out)      // [B, S, 3]
{
    const int b = blockIdx.x;
    const int tid = threadIdx.x;
    const int lane = tid & 63;
    const int wave = tid >> 6;
    const float* base = xyz + (size_t)b * NPTS * 3;

    __shared__ unsigned short s_sidx[NPTS];          // 32 KB sorted orig idx
    __shared__ unsigned int s_hist[NCELL];           // 16 KB hist -> starts
    __shared__ unsigned int s_part[FPS_THREADS];     // 4 KB scan partials
    __shared__ unsigned long long s_key[2][NWAVE];
    __shared__ unsigned long long s_fin[2];

    // ---- phase 0/1: cell ids + histogram (16^3 grid over [-3,3]) ----
    for (int i = tid; i < NCELL; i += FPS_THREADS) s_hist[i] = 0u;
    __syncthreads();

    unsigned cells[PPT];
#pragma unroll
    for (int p = 0; p < PPT; ++p) {
        const int i = tid + p * FPS_THREADS;
        const float x = base[i * 3 + 0];
        const float y = base[i * 3 + 1];
        const float z = base[i * 3 + 2];
        const int qx = (int)fminf(fmaxf((x + 3.0f) * 2.6666667f, 0.0f), 15.0f);
        const int qy = (int)fminf(fmaxf((y + 3.0f) * 2.6666667f, 0.0f), 15.0f);
        const int qz = (int)fminf(fmaxf((z + 3.0f) * 2.6666667f, 0.0f), 15.0f);
        unsigned m = 0;
#pragma unroll
        for (int t = 0; t < 4; ++t)
            m |= (((unsigned)(qx >> t) & 1u) << (3 * t + 2)) |
                 (((unsigned)(qy >> t) & 1u) << (3 * t + 1)) |
                 (((unsigned)(qz >> t) & 1u) << (3 * t + 0));
        cells[p] = m;
        atomicAdd(&s_hist[m], 1u);
    }
    __syncthreads();

    // ---- phase 2: exclusive scan over 4096 cells (two-stage) ----
    unsigned hh[CPT];
    unsigned tsum = 0;
#pragma unroll
    for (int j = 0; j < CPT; ++j) {
        hh[j] = s_hist[tid * CPT + j];
        tsum += hh[j];
    }
    s_part[tid] = tsum;
    __syncthreads();
    for (int off = 1; off < FPS_THREADS; off <<= 1) {
        unsigned v = s_part[tid];
        if (tid >= off) v += s_part[tid - off];
        __syncthreads();
        s_part[tid] = v;
        __syncthreads();
    }
    {
        unsigned e = (tid == 0) ? 0u : s_part[tid - 1];
#pragma unroll
        for (int j = 0; j < CPT; ++j) {
            s_hist[tid * CPT + j] = e;
            e += hh[j];
        }
    }
    __syncthreads();

    // ---- phase 3: scatter orig indices into cell-sorted order ----
#pragma unroll
    for (int p = 0; p < PPT; ++p) {
        const int i = tid + p * FPS_THREADS;
        const unsigned pos = atomicAdd(&s_hist[cells[p]], 1u);
        s_sidx[pos] = (unsigned short)i;
    }
    __syncthreads();

    // ---- phase 4: regather wave-contiguous points ----
    float px[PPT], py[PPT], pz[PPT], dist[PPT];
    unsigned oidx[PPT / 2];                          // packed u16 orig indices
#pragma unroll
    for (int p = 0; p < PPT; ++p) {
        const int spos = wave * 1024 + p * 64 + lane;
        const unsigned oi = (unsigned)s_sidx[spos];
        px[p] = base[oi * 3 + 0];
        py[p] = base[oi * 3 + 1];
        pz[p] = base[oi * 3 + 2];
        dist[p] = 1e10f;
        if (p & 1) oidx[p >> 1] |= oi << 16; else oidx[p >> 1] = oi;
    }

    // ---- phase 5: per-slice bboxes in lane p, wave bbox in all lanes ----
    float sbmnx = 0.f, sbmny = 0.f, sbmnz = 0.f;
    float sbmxx = 0.f, sbmxy = 0.f, sbmxz = 0.f;
    float wbmnx = 1e30f, wbmny = 1e30f, wbmnz = 1e30f;
    float wbmxx = -1e30f, wbmxy = -1e30f, wbmxz = -1e30f;
#pragma unroll
    for (int p = 0; p < PPT; ++p) {
        const float mnx = wave_min_all(px[p]);
        const float mny = wave_min_all(py[p]);
        const float mnz = wave_min_all(pz[p]);
        const float mxx = wave_max_all(px[p]);
        const float mxy = wave_max_all(py[p]);
        const float mxz = wave_max_all(pz[p]);
        const bool sel = (lane == p);
        sbmnx = sel ? mnx : sbmnx;  sbmny = sel ? mny : sbmny;
        sbmnz = sel ? mnz : sbmnz;  sbmxx = sel ? mxx : sbmxx;
        sbmxy = sel ? mxy : sbmxy;  sbmxz = sel ? mxz : sbmxz;
        wbmnx = fminf(wbmnx, mnx); wbmny = fminf(wbmny, mny);
        wbmnz = fminf(wbmnz, mnz); wbmxx = fmaxf(wbmxx, mxx);
        wbmxy = fmaxf(wbmxy, mxy); wbmxz = fmaxf(wbmxz, mxz);
    }

    float wmax_u = 1e10f;                // wave's current max dist (uniform)
    unsigned long long ckey = 0ull;      // cached wave key (lane63's is real)

    int cur = init_far[b];
    float cx = base[cur * 3 + 0];
    float cy = base[cur * 3 + 1];
    float cz = base[cur * 3 + 2];
    __syncthreads();

    for (int s = 0; s < NSAMP; ++s) {
        const int q = s & 1;
        // record BEFORE update (reference scan semantics)
        if (tid == 0) {
            idx_out[b * NSAMP + s] = cur;
            float* o = newxyz_out + (size_t)(b * NSAMP + s) * 3;
            o[0] = cx; o[1] = cy; o[2] = cz;
        }

        // level 1: wave bbox lower bound (uniform -> s_cbranch)
        const float wdx = fmaxf(fmaxf(wbmnx - cx, cx - wbmxx), 0.0f);
        const float wdy = fmaxf(fmaxf(wbmny - cy, cy - wbmxy), 0.0f);
        const float wdz = fmaxf(fmaxf(wbmnz - cz, cz - wbmxz), 0.0f);
        const float Lw = wdx * wdx + wdy * wdy + wdz * wdz;

        if (Lw * 0.99999f <= wmax_u) {
            // level 2: per-slice bounds via lane p + ballot
            const float dxl = fmaxf(fmaxf(sbmnx - cx, cx - sbmxx), 0.0f);
            const float dyl = fmaxf(fmaxf(sbmny - cy, cy - sbmxy), 0.0f);
            const float dzl = fmaxf(fmaxf(sbmnz - cz, cz - sbmxz), 0.0f);
            const float L = dxl * dxl + dyl * dyl + dzl * dzl;
            const unsigned long long bal = __ballot(L * 0.99999f <= wmax_u);
            const unsigned amask =
                __builtin_amdgcn_readfirstlane((unsigned)bal) & 0xFFFFu;

            // dist update per flagged slice (wave-uniform branches)
#pragma unroll
            for (int p = 0; p < PPT; ++p) {
                if (amask & (1u << p)) {
                    const float dx = __fsub_rn(px[p], cx);
                    const float dy = __fsub_rn(py[p], cy);
                    const float dz = __fsub_rn(pz[p], cz);
                    const float d  = __fadd_rn(__fadd_rn(__fmul_rn(dx, dx),
                                                         __fmul_rn(dy, dy)),
                                               __fmul_rn(dz, dz));
                    dist[p] = fminf(dist[p], d);
                }
            }

            // exact per-thread max over all 16 slices
            float best = 0.0f;
#pragma unroll
            for (int p = 0; p < PPT; p += 2)
                best = fmaxf(fmaxf(best, dist[p]), dist[p + 1]);   // v_max3

            // min ORIGINAL index among exact matches (jnp.argmax tie rule)
            unsigned bo = 0xFFFFFFFFu;
#pragma unroll
            for (int p = 0; p < PPT; ++p) {
                const unsigned oi = (oidx[p >> 1] >> ((p & 1) * 16)) & 0xFFFFu;
                bo = (dist[p] == best) ? min(bo, oi) : bo;
            }
            unsigned long long key =
                ((unsigned long long)__float_as_uint(best) << 32) |
                (unsigned long long)(~bo);
            key = dpp_key_max<0x111>(key);
            key = dpp_key_max<0x112>(key);
            key = dpp_key_max<0x114>(key);
            key = dpp_key_max<0x118>(key);
            key = dpp_key_max<0x142>(key);
            key = dpp_key_max<0x143>(key);
            ckey = key;                              // lane63 holds wave key
            wmax_u = __shfl(__uint_as_float((unsigned)(key >> 32)), 63, 64);
        }

        if (lane == 63) s_key[q][wave] = ckey;
        __syncthreads();                             // barrier 1

        // block reduce: wave0 only — lanes read the 16 keys, 4-level DPP
        // row-max; lane15 holds the final key and publishes it.
        if (wave == 0) {
            unsigned long long k = s_key[q][lane & 15];
            k = dpp_key_max<0x111>(k);   // row_shr:1
            k = dpp_key_max<0x112>(k);   // row_shr:2
            k = dpp_key_max<0x114>(k);   // row_shr:4
            k = dpp_key_max<0x118>(k);   // row_shr:8
            if (lane == 15) s_fin[q] = k;
        }
        __syncthreads();                             // barrier 2

        const unsigned long long fin = s_fin[q];     // broadcast LDS read
        const int vi = (int)(~(unsigned)(fin & 0xFFFFFFFFull));
        cur = vi;
        const int vs = __builtin_amdgcn_readfirstlane(vi);
        cx = base[vs * 3 + 0];
        cy = base[vs * 3 + 1];
        cz = base[vs * 3 + 2];
    }
}

// ---------------------------------------------------------------------------
// Kernel 2: gather selected rows, 1x1 conv (x @ W + b), ReLU.
// ---------------------------------------------------------------------------
#define SAMP_PER_BLK 16

__global__ __launch_bounds__(256)
void gather_linear_relu_kernel(const float* __restrict__ xyz,    // [B,N,3]
                               const float* __restrict__ feats,  // [B,N,F]
                               const int* __restrict__ idx,      // [B*S]
                               const float* __restrict__ W,      // [67,128]
                               const float* __restrict__ bias,   // [128]
                               float* __restrict__ out)          // [B*S,128]
{
    __shared__ float sW[C_IN][D_OUT];
    __shared__ float sX[SAMP_PER_BLK][C_IN + 1];
    __shared__ float sB[D_OUT];

    const int tid = threadIdx.x;

    for (int i = tid; i < C_IN * D_OUT; i += 256)
        (&sW[0][0])[i] = W[i];
    if (tid < D_OUT) sB[tid] = bias[tid];

    const int gs0 = blockIdx.x * SAMP_PER_BLK;

    {
        const int si = tid >> 4;
        const int j  = tid & 15;
        const int gs = gs0 + si;
        const int bb = gs >> 11;
        const int pt = idx[gs];
        const float* frow = feats + ((size_t)bb * NPTS + pt) * F_IN;
        const float* xrow = xyz   + ((size_t)bb * NPTS + pt) * 3;
        for (int c = j; c < F_IN; c += 16) sX[si][c] = frow[c];
        if (j < 3) sX[si][F_IN + j] = xrow[j];
    }
    __syncthreads();

    const int d = tid & 127;
    const int g = tid >> 7;
    float acc[8];
#pragma unroll
    for (int k = 0; k < 8; ++k) acc[k] = 0.0f;

    for (int c = 0; c < C_IN; ++c) {
        const float w = sW[c][d];
#pragma unroll
        for (int k = 0; k < 8; ++k)
            acc[k] = fmaf(sX[g * 8 + k][c], w, acc[k]);
    }

    const float bv = sB[d];
#pragma unroll
    for (int k = 0; k < 8; ++k) {
        const int gs = gs0 + g * 8 + k;
        const float v = acc[k] + bv;
        out[(size_t)gs * D_OUT + d] = fmaxf(v, 0.0f);
    }
}

// ---------------------------------------------------------------------------
extern "C" void kernel_launch(void* const* d_in, const int* in_sizes, int n_in,
                              void* d_out, int out_size, void* d_ws, size_t ws_size,
                              hipStream_t stream) {
    const float* xyz      = (const float*)d_in[0];
    const float* feats    = (const float*)d_in[1];
    const int*   init_far = (const int*)d_in[2];
    const float* W        = (const float*)d_in[3];
    const float* bias     = (const float*)d_in[4];

    float* out_newxyz = (float*)d_out;
    float* out_conv   = (float*)d_out + (size_t)B_SZ * NSAMP * 3;
    int*   idx_ws     = (int*)d_ws;

    fps_kernel<<<B_SZ, FPS_THREADS, 0, stream>>>(xyz, init_far, idx_ws, out_newxyz);

    const int nblocks = (B_SZ * NSAMP) / SAMP_PER_BLK;
    gather_linear_relu_kernel<<<nblocks, 256, 0, stream>>>(
        xyz, feats, idx_ws, W, bias, out_conv);
}

// Round 18
// 2065.271 us; speedup vs baseline: 2.5079x; 1.0737x over previous
//
#include <hip/hip_runtime.h>
#include <cstdint>
#include <cstddef>

#define B_SZ 32
#define NPTS 16384
#define NSAMP 2048
#define F_IN 64
#define C_IN 67
#define D_OUT 128
#define FPS_THREADS 1024
#define PPT 16                     // points (slices) per thread (wave)
#define NWAVE 16
#define NCELL 4096                 // 16x16x16 Morton cells
#define CPT (NCELL / FPS_THREADS)  // 4 cells per thread in the scan

// ---- DPP wave reduce helpers ----
template <int CTRL>
__device__ __forceinline__ float dpp_maxf(float v) {
    const int iv = __float_as_int(v);
    const int mv = __builtin_amdgcn_update_dpp(iv, iv, CTRL, 0xf, 0xf, false);
    return fmaxf(v, __int_as_float(mv));
}
template <int CTRL>
__device__ __forceinline__ float dpp_minf(float v) {
    const int iv = __float_as_int(v);
    const int mv = __builtin_amdgcn_update_dpp(iv, iv, CTRL, 0xf, 0xf, false);
    return fminf(v, __int_as_float(mv));
}
__device__ __forceinline__ float wave_max_all(float v) {
    v = dpp_maxf<0x111>(v); v = dpp_maxf<0x112>(v); v = dpp_maxf<0x114>(v);
    v = dpp_maxf<0x118>(v); v = dpp_maxf<0x142>(v); v = dpp_maxf<0x143>(v);
    return __shfl(v, 63, 64);
}
__device__ __forceinline__ float wave_min_all(float v) {
    v = dpp_minf<0x111>(v); v = dpp_minf<0x112>(v); v = dpp_minf<0x114>(v);
    v = dpp_minf<0x118>(v); v = dpp_minf<0x142>(v); v = dpp_minf<0x143>(v);
    return __shfl(v, 63, 64);
}
template <int CTRL>
__device__ __forceinline__ unsigned long long dpp_key_max(unsigned long long key) {
    const int lo = (int)(unsigned)key;
    const int hi = (int)(unsigned)(key >> 32);
    const int lo2 = __builtin_amdgcn_update_dpp(lo, lo, CTRL, 0xf, 0xf, false);
    const int hi2 = __builtin_amdgcn_update_dpp(hi, hi, CTRL, 0xf, 0xf, false);
    const unsigned long long ok =
        ((unsigned long long)(unsigned)hi2 << 32) | (unsigned long long)(unsigned)lo2;
    return ok > key ? ok : key;
}

// ---------------------------------------------------------------------------
// FPS, R17 two-level exact skip + SINGLE-barrier lane-parallel block reduce:
//   - every wave reduces the 16 wave keys itself: each lane reads ONE key
//     (s_key[q][lane&15], one ds_read_b64; rows alias -> broadcast), then a
//     4-level DPP row-max; lane 15 of each row holds the final key.
//     v_readlane(…,15) extracts vi and wmax straight into SGPRs -> the
//     centroid load stays on the scalar (SMEM) pipe.
//   - removes R17's barrier2 + s_fin round-trip and R13's 16-read/15-deep
//     serial chain. One barrier per iteration again (parity key slots).
//   - skip tests / dist update / tie-break identical to R16/R17:
//     conservative 1e-5 slack >> fp error -> fminf provably no-op on skipped
//     sets; min-ORIGINAL-index tie-break == jnp.argmax -> bit-identical
//     trajectory (absmax 0 since R11).
// ---------------------------------------------------------------------------
__global__ __launch_bounds__(FPS_THREADS, 4)
void fps_kernel(const float* __restrict__ xyz,       // [B, N, 3]
                const int* __restrict__ init_far,    // [B]
                int* __restrict__ idx_out,           // [B, S]
                float* __restrict__ newxyz_out)      // [B, S, 3]
{
    const int b = blockIdx.x;
    const int tid = threadIdx.x;
    const int lane = tid & 63;
    const int wave = tid >> 6;
    const float* base = xyz + (size_t)b * NPTS * 3;

    __shared__ unsigned short s_sidx[NPTS];          // 32 KB sorted orig idx
    __shared__ unsigned int s_hist[NCELL];           // 16 KB hist -> starts
    __shared__ unsigned int s_part[FPS_THREADS];     // 4 KB scan partials
    __shared__ unsigned long long s_key[2][NWAVE];

    // ---- phase 0/1: cell ids + histogram (16^3 grid over [-3,3]) ----
    for (int i = tid; i < NCELL; i += FPS_THREADS) s_hist[i] = 0u;
    __syncthreads();

    unsigned cells[PPT];
#pragma unroll
    for (int p = 0; p < PPT; ++p) {
        const int i = tid + p * FPS_THREADS;
        const float x = base[i * 3 + 0];
        const float y = base[i * 3 + 1];
        const float z = base[i * 3 + 2];
        const int qx = (int)fminf(fmaxf((x + 3.0f) * 2.6666667f, 0.0f), 15.0f);
        const int qy = (int)fminf(fmaxf((y + 3.0f) * 2.6666667f, 0.0f), 15.0f);
        const int qz = (int)fminf(fmaxf((z + 3.0f) * 2.6666667f, 0.0f), 15.0f);
        unsigned m = 0;
#pragma unroll
        for (int t = 0; t < 4; ++t)
            m |= (((unsigned)(qx >> t) & 1u) << (3 * t + 2)) |
                 (((unsigned)(qy >> t) & 1u) << (3 * t + 1)) |
                 (((unsigned)(qz >> t) & 1u) << (3 * t + 0));
        cells[p] = m;
        atomicAdd(&s_hist[m], 1u);
    }
    __syncthreads();

    // ---- phase 2: exclusive scan over 4096 cells (two-stage) ----
    unsigned hh[CPT];
    unsigned tsum = 0;
#pragma unroll
    for (int j = 0; j < CPT; ++j) {
        hh[j] = s_hist[tid * CPT + j];
        tsum += hh[j];
    }
    s_part[tid] = tsum;
    __syncthreads();
    for (int off = 1; off < FPS_THREADS; off <<= 1) {
        unsigned v = s_part[tid];
        if (tid >= off) v += s_part[tid - off];
        __syncthreads();
        s_part[tid] = v;
        __syncthreads();
    }
    {
        unsigned e = (tid == 0) ? 0u : s_part[tid - 1];
#pragma unroll
        for (int j = 0; j < CPT; ++j) {
            s_hist[tid * CPT + j] = e;
            e += hh[j];
        }
    }
    __syncthreads();

    // ---- phase 3: scatter orig indices into cell-sorted order ----
#pragma unroll
    for (int p = 0; p < PPT; ++p) {
        const int i = tid + p * FPS_THREADS;
        const unsigned pos = atomicAdd(&s_hist[cells[p]], 1u);
        s_sidx[pos] = (unsigned short)i;
    }
    __syncthreads();

    // ---- phase 4: regather wave-contiguous points ----
    float px[PPT], py[PPT], pz[PPT], dist[PPT];
    unsigned oidx[PPT / 2];                          // packed u16 orig indices
#pragma unroll
    for (int p = 0; p < PPT; ++p) {
        const int spos = wave * 1024 + p * 64 + lane;
        const unsigned oi = (unsigned)s_sidx[spos];
        px[p] = base[oi * 3 + 0];
        py[p] = base[oi * 3 + 1];
        pz[p] = base[oi * 3 + 2];
        dist[p] = 1e10f;
        if (p & 1) oidx[p >> 1] |= oi << 16; else oidx[p >> 1] = oi;
    }

    // ---- phase 5: per-slice bboxes in lane p, wave bbox in all lanes ----
    float sbmnx = 0.f, sbmny = 0.f, sbmnz = 0.f;
    float sbmxx = 0.f, sbmxy = 0.f, sbmxz = 0.f;
    float wbmnx = 1e30f, wbmny = 1e30f, wbmnz = 1e30f;
    float wbmxx = -1e30f, wbmxy = -1e30f, wbmxz = -1e30f;
#pragma unroll
    for (int p = 0; p < PPT; ++p) {
        const float mnx = wave_min_all(px[p]);
        const float mny = wave_min_all(py[p]);
        const float mnz = wave_min_all(pz[p]);
        const float mxx = wave_max_all(px[p]);
        const float mxy = wave_max_all(py[p]);
        const float mxz = wave_max_all(pz[p]);
        const bool sel = (lane == p);
        sbmnx = sel ? mnx : sbmnx;  sbmny = sel ? mny : sbmny;
        sbmnz = sel ? mnz : sbmnz;  sbmxx = sel ? mxx : sbmxx;
        sbmxy = sel ? mxy : sbmxy;  sbmxz = sel ? mxz : sbmxz;
        wbmnx = fminf(wbmnx, mnx); wbmny = fminf(wbmny, mny);
        wbmnz = fminf(wbmnz, mnz); wbmxx = fmaxf(wbmxx, mxx);
        wbmxy = fmaxf(wbmxy, mxy); wbmxz = fmaxf(wbmxz, mxz);
    }

    float wmax_u = 1e10f;                // wave's current max dist (uniform)
    unsigned long long ckey = 0ull;      // cached wave key (lane63's is real)

    int cur = init_far[b];
    float cx = base[cur * 3 + 0];
    float cy = base[cur * 3 + 1];
    float cz = base[cur * 3 + 2];
    __syncthreads();

    for (int s = 0; s < NSAMP; ++s) {
        const int q = s & 1;
        // record BEFORE update (reference scan semantics)
        if (tid == 0) {
            idx_out[b * NSAMP + s] = cur;
            float* o = newxyz_out + (size_t)(b * NSAMP + s) * 3;
            o[0] = cx; o[1] = cy; o[2] = cz;
        }

        // level 1: wave bbox lower bound (uniform -> s_cbranch)
        const float wdx = fmaxf(fmaxf(wbmnx - cx, cx - wbmxx), 0.0f);
        const float wdy = fmaxf(fmaxf(wbmny - cy, cy - wbmxy), 0.0f);
        const float wdz = fmaxf(fmaxf(wbmnz - cz, cz - wbmxz), 0.0f);
        const float Lw = wdx * wdx + wdy * wdy + wdz * wdz;

        if (Lw * 0.99999f <= wmax_u) {
            // level 2: per-slice bounds via lane p + ballot
            const float dxl = fmaxf(fmaxf(sbmnx - cx, cx - sbmxx), 0.0f);
            const float dyl = fmaxf(fmaxf(sbmny - cy, cy - sbmxy), 0.0f);
            const float dzl = fmaxf(fmaxf(sbmnz - cz, cz - sbmxz), 0.0f);
            const float L = dxl * dxl + dyl * dyl + dzl * dzl;
            const unsigned long long bal = __ballot(L * 0.99999f <= wmax_u);
            const unsigned amask =
                __builtin_amdgcn_readfirstlane((unsigned)bal) & 0xFFFFu;

            // dist update per flagged slice (wave-uniform branches)
#pragma unroll
            for (int p = 0; p < PPT; ++p) {
                if (amask & (1u << p)) {
                    const float dx = __fsub_rn(px[p], cx);
                    const float dy = __fsub_rn(py[p], cy);
                    const float dz = __fsub_rn(pz[p], cz);
                    const float d  = __fadd_rn(__fadd_rn(__fmul_rn(dx, dx),
                                                         __fmul_rn(dy, dy)),
                                               __fmul_rn(dz, dz));
                    dist[p] = fminf(dist[p], d);
                }
            }

            // exact per-thread max over all 16 slices
            float best = 0.0f;
#pragma unroll
            for (int p = 0; p < PPT; p += 2)
                best = fmaxf(fmaxf(best, dist[p]), dist[p + 1]);   // v_max3

            // min ORIGINAL index among exact matches (jnp.argmax tie rule)
            unsigned bo = 0xFFFFFFFFu;
#pragma unroll
            for (int p = 0; p < PPT; ++p) {
                const unsigned oi = (oidx[p >> 1] >> ((p & 1) * 16)) & 0xFFFFu;
                bo = (dist[p] == best) ? min(bo, oi) : bo;
            }
            unsigned long long key =
                ((unsigned long long)__float_as_uint(best) << 32) |
                (unsigned long long)(~bo);
            key = dpp_key_max<0x111>(key);
            key = dpp_key_max<0x112>(key);
            key = dpp_key_max<0x114>(key);
            key = dpp_key_max<0x118>(key);
            key = dpp_key_max<0x142>(key);
            key = dpp_key_max<0x143>(key);
            ckey = key;                              // lane63 holds wave key
            wmax_u = __shfl(__uint_as_float((unsigned)(key >> 32)), 63, 64);
        }

        if (lane == 63) s_key[q][wave] = ckey;
        __syncthreads();                             // the only barrier

        // lane-parallel block reduce: each lane reads ONE key, 4-level DPP
        // row-max; lane 15 of every 16-lane row holds the final key.
        unsigned long long k = s_key[q][lane & 15];
        k = dpp_key_max<0x111>(k);   // row_shr:1
        k = dpp_key_max<0x112>(k);   // row_shr:2
        k = dpp_key_max<0x114>(k);   // row_shr:4
        k = dpp_key_max<0x118>(k);   // row_shr:8
        // extract straight to SGPRs from lane 15
        const int nlo = __builtin_amdgcn_readlane((int)(unsigned)k, 15);
        const int nhi = __builtin_amdgcn_readlane((int)(unsigned)(k >> 32), 15);
        const int vs = (int)(~(unsigned)nlo) & 0xFFFF;
        cur = vs;
        // scalar (SMEM) centroid load — vs is SGPR-uniform by construction
        cx = base[vs * 3 + 0];
        cy = base[vs * 3 + 1];
        cz = base[vs * 3 + 2];
        (void)nhi;
    }
}

// ---------------------------------------------------------------------------
// Kernel 2: gather selected rows, 1x1 conv (x @ W + b), ReLU.
// ---------------------------------------------------------------------------
#define SAMP_PER_BLK 16

__global__ __launch_bounds__(256)
void gather_linear_relu_kernel(const float* __restrict__ xyz,    // [B,N,3]
                               const float* __restrict__ feats,  // [B,N,F]
                               const int* __restrict__ idx,      // [B*S]
                               const float* __restrict__ W,      // [67,128]
                               const float* __restrict__ bias,   // [128]
                               float* __restrict__ out)          // [B*S,128]
{
    __shared__ float sW[C_IN][D_OUT];
    __shared__ float sX[SAMP_PER_BLK][C_IN + 1];
    __shared__ float sB[D_OUT];

    const int tid = threadIdx.x;

    for (int i = tid; i < C_IN * D_OUT; i += 256)
        (&sW[0][0])[i] = W[i];
    if (tid < D_OUT) sB[tid] = bias[tid];

    const int gs0 = blockIdx.x * SAMP_PER_BLK;

    {
        const int si = tid >> 4;
        const int j  = tid & 15;
        const int gs = gs0 + si;
        const int bb = gs >> 11;
        const int pt = idx[gs];
        const float* frow = feats + ((size_t)bb * NPTS + pt) * F_IN;
        const float* xrow = xyz   + ((size_t)bb * NPTS + pt) * 3;
        for (int c = j; c < F_IN; c += 16) sX[si][c] = frow[c];
        if (j < 3) sX[si][F_IN + j] = xrow[j];
    }
    __syncthreads();

    const int d = tid & 127;
    const int g = tid >> 7;
    float acc[8];
#pragma unroll
    for (int k = 0; k < 8; ++k) acc[k] = 0.0f;

    for (int c = 0; c < C_IN; ++c) {
        const float w = sW[c][d];
#pragma unroll
        for (int k = 0; k < 8; ++k)
            acc[k] = fmaf(sX[g * 8 + k][c], w, acc[k]);
    }

    const float bv = sB[d];
#pragma unroll
    for (int k = 0; k < 8; ++k) {
        const int gs = gs0 + g * 8 + k;
        const float v = acc[k] + bv;
        out[(size_t)gs * D_OUT + d] = fmaxf(v, 0.0f);
    }
}

// ---------------------------------------------------------------------------
extern "C" void kernel_launch(void* const* d_in, const int* in_sizes, int n_in,
                              void* d_out, int out_size, void* d_ws, size_t ws_size,
                              hipStream_t stream) {
    const float* xyz      = (const float*)d_in[0];
    const float* feats    = (const float*)d_in[1];
    const int*   init_far = (const int*)d_in[2];
    const float* W        = (const float*)d_in[3];
    const float* bias     = (const float*)d_in[4];

    float* out_newxyz = (float*)d_out;
    float* out_conv   = (float*)d_out + (size_t)B_SZ * NSAMP * 3;
    int*   idx_ws     = (int*)d_ws;

    fps_kernel<<<B_SZ, FPS_THREADS, 0, stream>>>(xyz, init_far, idx_ws, out_newxyz);

    const int nblocks = (B_SZ * NSAMP) / SAMP_PER_BLK;
    gather_linear_relu_kernel<<<nblocks, 256, 0, stream>>>(
        xyz, feats, idx_ws, W, bias, out_conv);
}